// Round 1
// baseline (238.205 us; speedup 1.0000x reference)
//
#include <hip/hip_runtime.h>

#define NH 16
#define HS 64
#define T_CTX 2048
#define NE 1024
#define NB 2
#define BT (NB*T_CTX)      // 4096 rows
#define HD (NH*HS)         // 1024

typedef unsigned short u16;
typedef __bf16 bf16_t;
typedef bf16_t bf16x8 __attribute__((ext_vector_type(8)));
typedef float f32x4 __attribute__((ext_vector_type(4)));
typedef u16 u16x8 __attribute__((ext_vector_type(8)));

#define GLDS(gp, lp) __builtin_amdgcn_global_load_lds( \
    (const __attribute__((address_space(1))) void*)(gp), \
    (__attribute__((address_space(3))) void*)(lp), 16, 0, 0)

__device__ __forceinline__ u16 f2bf(float f) {
  union { float f; unsigned u; } x; x.f = f;
  return (u16)((x.u + 0x7fffu + ((x.u >> 16) & 1u)) >> 16);
}

// ---------------- prep: x fp32 -> bf16 (same layout) ----------------
__global__ __launch_bounds__(256) void k_prep_x(const float* __restrict__ x,
                                                u16* __restrict__ xb) {
  int i = blockIdx.x * blockDim.x + threadIdx.x;   // one float4 each
  float4 v = ((const float4*)x)[i];
  ushort4 o;
  o.x = f2bf(v.x); o.y = f2bf(v.y); o.z = f2bf(v.z); o.w = f2bf(v.w);
  ((ushort4*)xb)[i] = o;
}

// ------------- prep: W [K,N] fp32 -> Wt [N,K] bf16 (transpose) -------------
__global__ __launch_bounds__(256) void k_prep_w(
    const float* __restrict__ W0, const float* __restrict__ W1,
    const float* __restrict__ W2, const float* __restrict__ W3,
    u16* __restrict__ T0, u16* __restrict__ T1,
    u16* __restrict__ T2, u16* __restrict__ T3) {
  const float* W; u16* T;
  switch (blockIdx.z) {
    case 0: W = W0; T = T0; break;
    case 1: W = W1; T = T1; break;
    case 2: W = W2; T = T2; break;
    default: W = W3; T = T3; break;
  }
  __shared__ u16 tile[64 * 72];              // [n][k], stride 72 (16B-aligned rows)
  int k0 = blockIdx.x * 64, n0 = blockIdx.y * 64;
  int tid = threadIdx.x;
#pragma unroll
  for (int it = 0; it < 4; ++it) {
    int ci = tid + it * 256;                 // 1024 chunks of float4
    int k = ci >> 4, c = ci & 15;
    float4 v = *(const float4*)&W[(size_t)(k0 + k) * NE + n0 + c * 4];
    int n = c * 4;
    tile[(n + 0) * 72 + k] = f2bf(v.x);
    tile[(n + 1) * 72 + k] = f2bf(v.y);
    tile[(n + 2) * 72 + k] = f2bf(v.z);
    tile[(n + 3) * 72 + k] = f2bf(v.w);
  }
  __syncthreads();
#pragma unroll
  for (int it = 0; it < 2; ++it) {
    int co = tid + it * 256;                 // 512 chunks of 8 u16
    int n = co >> 3, c = co & 7;
    u16x8 v = *(const u16x8*)&tile[n * 72 + c * 8];
    *(u16x8*)&T[(size_t)(n0 + n) * NE + k0 + c * 8] = v;
  }
}

// ---------------- GEMM core: 128x128 tile, BK=32, m97 pattern ----------------
__device__ __forceinline__ void gemm_core(
    const u16* __restrict__ A, const u16* __restrict__ Bt,
    int m0, int n0, u16* As, u16* Bs, f32x4 (&acc)[4][4]) {
  const int tid = threadIdx.x, lane = tid & 63, w = tid >> 6;
  const int wm = (w >> 1) * 64, wn = (w & 1) * 64;
  const int q = lane >> 4, l16 = lane & 15;
#pragma unroll
  for (int i = 0; i < 4; ++i)
#pragma unroll
    for (int j = 0; j < 4; ++j)
#pragma unroll
      for (int r = 0; r < 4; ++r) acc[i][j][r] = 0.f;

  for (int k0 = 0; k0 < NE; k0 += 32) {
#pragma unroll
    for (int s2 = 0; s2 < 2; ++s2) {
      int ci = w * 64 + lane + s2 * 256;     // 512 chunks of 16B per matrix
      int row = ci >> 2, cc = ci & 3;
      GLDS(A  + (size_t)(m0 + row) * NE + k0 + cc * 8, As + (size_t)(w * 64 + s2 * 256) * 8);
      GLDS(Bt + (size_t)(n0 + row) * NE + k0 + cc * 8, Bs + (size_t)(w * 64 + s2 * 256) * 8);
    }
    __syncthreads();
    bf16x8 av[4], bv4[4];
#pragma unroll
    for (int i = 0; i < 4; ++i) av[i]  = *(const bf16x8*)&As[(wm + i * 16 + l16) * 32 + q * 8];
#pragma unroll
    for (int j = 0; j < 4; ++j) bv4[j] = *(const bf16x8*)&Bs[(wn + j * 16 + l16) * 32 + q * 8];
#pragma unroll
    for (int i = 0; i < 4; ++i)
#pragma unroll
      for (int j = 0; j < 4; ++j)
        acc[i][j] = __builtin_amdgcn_mfma_f32_16x16x32_bf16(av[i], bv4[j], acc[i][j], 0, 0, 0);
    __syncthreads();
  }
}

// ------ QKV projection: C = x@W + b ; write bf16 [B,H,T,D]; scale folded into Q ------
__global__ __launch_bounds__(256) void k_gemm_qkv(
    const u16* __restrict__ xb, const u16* __restrict__ Wt,
    const float* __restrict__ bq, const float* __restrict__ bk,
    const float* __restrict__ bv, u16* __restrict__ qkv) {
  __shared__ u16 As[128 * 32], Bs[128 * 32];
  const int z = blockIdx.z;
  const u16* W = Wt + (size_t)z * NE * HD;
  const float* bias = (z == 0) ? bq : (z == 1 ? bk : bv);
  u16* dst = qkv + (size_t)z * BT * HD;
  // softmax scale 1/sqrt(E) and log2(e) folded into Q so attention uses exp2
  const float scale = (z == 0) ? 0.03125f * 1.4426950408889634f : 1.0f;
  const int m0 = blockIdx.x * 128, n0 = blockIdx.y * 128;
  f32x4 acc[4][4];
  gemm_core(xb, W, m0, n0, As, Bs, acc);
  const int lane = threadIdx.x & 63, w = threadIdx.x >> 6;
  const int wm = (w >> 1) * 64, wn = (w & 1) * 64, q = lane >> 4, l16 = lane & 15;
#pragma unroll
  for (int j = 0; j < 4; ++j) {
    int n = n0 + wn + j * 16 + l16;
    float bn = bias[n];
    int h = n >> 6, d = n & 63;
#pragma unroll
    for (int i = 0; i < 4; ++i)
#pragma unroll
      for (int r = 0; r < 4; ++r) {
        int m = m0 + wm + i * 16 + q * 4 + r;
        int bb = m >> 11, t = m & (T_CTX - 1);
        dst[(((size_t)(bb * NH + h)) * T_CTX + t) * HS + d] =
            f2bf((acc[i][j][r] + bn) * scale);
      }
  }
}

// ---------------- V [B,H,T,D] -> Vt [B,H,D,T] ----------------
__global__ __launch_bounds__(256) void k_vt(const u16* __restrict__ V,
                                            u16* __restrict__ Vt) {
  int bh = blockIdx.y, t0 = blockIdx.x * 64;
  const u16* src = V + (size_t)bh * T_CTX * HS;
  u16* dst = Vt + (size_t)bh * HS * T_CTX;
  __shared__ u16 tile[64 * 72];              // [d][t]
  int tid = threadIdx.x;
#pragma unroll
  for (int it = 0; it < 2; ++it) {
    int ci = tid + it * 256;                 // 512 chunks
    int t = ci >> 3, c = ci & 7;
    u16x8 v = *(const u16x8*)&src[(size_t)(t0 + t) * HS + c * 8];
#pragma unroll
    for (int e = 0; e < 8; ++e) tile[(c * 8 + e) * 72 + t] = v[e];
  }
  __syncthreads();
#pragma unroll
  for (int it = 0; it < 2; ++it) {
    int co = tid + it * 256;
    int d = co >> 3, c = co & 7;
    u16x8 v = *(const u16x8*)&tile[d * 72 + c * 8];
    *(u16x8*)&dst[(size_t)d * T_CTX + t0 + c * 8] = v;
  }
}

// ---------------- flash attention: one block per (bh, q-tile of 128) ----------------
// LDS exactly 64KB: Ks 16K + Vs 16K + Ps 32K, XOR-swizzled (no pad) -> 2 blocks/CU
__global__ __launch_bounds__(256, 2) void k_attn(
    const u16* __restrict__ Qw, const u16* __restrict__ Kw,
    const u16* __restrict__ Vtw, u16* __restrict__ att) {
  __shared__ u16 Ks[128 * 64];               // [key][d], chunk ^= row&7
  __shared__ u16 Vs[64 * 128];               // [d][key], chunk ^= row&15
  __shared__ u16 Ps[128 * 128];              // [qrow][key], chunk ^= row&15

  const int bh = blockIdx.y;
  const int qt = (int)gridDim.x - 1 - (int)blockIdx.x;  // big tiles dispatch first
  const int b = bh >> 4, h = bh & (NH - 1);
  const u16* Qp = Qw + (size_t)bh * T_CTX * HS;
  const u16* Kp = Kw + (size_t)bh * T_CTX * HS;
  const u16* Vp = Vtw + (size_t)bh * HS * T_CTX;

  const int tid = threadIdx.x, lane = tid & 63, w = tid >> 6;
  const int q = lane >> 4, c = lane & 15;
  const int rbase = w * 32;                  // wave's 32 q-rows within tile

  // Q fragments straight from global (scale already folded in)
  bf16x8 aq[2][2];
#pragma unroll
  for (int i = 0; i < 2; ++i)
#pragma unroll
    for (int s = 0; s < 2; ++s)
      aq[i][s] = *(const bf16x8*)&Qp[(size_t)(qt * 128 + rbase + i * 16 + c) * HS + s * 32 + q * 8];

  f32x4 o[2][4];
  float mrow[2][4], lrow[2][4];
#pragma unroll
  for (int i = 0; i < 2; ++i)
#pragma unroll
    for (int r = 0; r < 4; ++r) {
      mrow[i][r] = -__builtin_inff(); lrow[i][r] = 0.f;
#pragma unroll
      for (int j = 0; j < 4; ++j) o[i][j][r] = 0.f;
    }

  for (int kt = 0; kt <= qt; ++kt) {
    const int k0 = kt * 128;
    // stage K tile [128][64] and V^T tile [64][128], swizzled
#pragma unroll
    for (int it = 0; it < 4; ++it) {
      int ci = tid + it * 256;
      int row = ci >> 3, cc = ci & 7;
      *(u16x8*)&Ks[row * 64 + (cc ^ (row & 7)) * 8] =
          *(const u16x8*)&Kp[(size_t)(k0 + row) * HS + cc * 8];
      int d = ci >> 4, c2 = ci & 15;
      *(u16x8*)&Vs[d * 128 + (c2 ^ (d & 15)) * 8] =
          *(const u16x8*)&Vp[(size_t)d * T_CTX + k0 + c2 * 8];
    }
    __syncthreads();

    // S = Q K^T (wave: 32 rows x 128 cols)
    f32x4 s[2][8];
#pragma unroll
    for (int i = 0; i < 2; ++i)
#pragma unroll
      for (int j = 0; j < 8; ++j)
#pragma unroll
        for (int r = 0; r < 4; ++r) s[i][j][r] = 0.f;
#pragma unroll
    for (int j = 0; j < 8; ++j) {
      int krow = j * 16 + c;
      bf16x8 b0 = *(const bf16x8*)&Ks[krow * 64 + ((0 + q) ^ (krow & 7)) * 8];
      bf16x8 b1 = *(const bf16x8*)&Ks[krow * 64 + ((4 + q) ^ (krow & 7)) * 8];
#pragma unroll
      for (int i = 0; i < 2; ++i) {
        s[i][j] = __builtin_amdgcn_mfma_f32_16x16x32_bf16(aq[i][0], b0, s[i][j], 0, 0, 0);
        s[i][j] = __builtin_amdgcn_mfma_f32_16x16x32_bf16(aq[i][1], b1, s[i][j], 0, 0, 0);
      }
    }

    if (kt == qt) {  // causal mask on diagonal tile only
#pragma unroll
      for (int i = 0; i < 2; ++i)
#pragma unroll
        for (int j = 0; j < 8; ++j)
#pragma unroll
          for (int r = 0; r < 4; ++r) {
            int col = k0 + j * 16 + c;
            int row = qt * 128 + rbase + i * 16 + q * 4 + r;
            if (col > row) s[i][j][r] = -__builtin_inff();
          }
    }

    // online softmax (log2 domain); row state aligns with C-layout (row = q*4+r)
    float mnew[2][4], alpha[2][4];
#pragma unroll
    for (int i = 0; i < 2; ++i)
#pragma unroll
      for (int r = 0; r < 4; ++r) {
        float mx = s[i][0][r];
#pragma unroll
        for (int j = 1; j < 8; ++j) mx = fmaxf(mx, s[i][j][r]);
#pragma unroll
        for (int off = 1; off < 16; off <<= 1) mx = fmaxf(mx, __shfl_xor(mx, off, 64));
        float mn = fmaxf(mrow[i][r], mx);
        alpha[i][r] = exp2f(mrow[i][r] - mn);
        mrow[i][r] = mn;
        mnew[i][r] = mn;
      }

    float rsum[2][4];
#pragma unroll
    for (int i = 0; i < 2; ++i)
#pragma unroll
      for (int r = 0; r < 4; ++r) rsum[i][r] = 0.f;
#pragma unroll
    for (int i = 0; i < 2; ++i)
#pragma unroll
      for (int j = 0; j < 8; ++j)
#pragma unroll
        for (int r = 0; r < 4; ++r) {
          float p = exp2f(s[i][j][r] - mnew[i][r]);
          rsum[i][r] += p;
          int pr = rbase + i * 16 + q * 4 + r;
          int ch = j * 2 + (c >> 3);
          Ps[pr * 128 + ((ch ^ (pr & 15)) * 8) + (c & 7)] = f2bf(p);
        }
#pragma unroll
    for (int i = 0; i < 2; ++i)
#pragma unroll
      for (int r = 0; r < 4; ++r) {
        float sm = rsum[i][r];
#pragma unroll
        for (int off = 1; off < 16; off <<= 1) sm += __shfl_xor(sm, off, 64);
        lrow[i][r] = lrow[i][r] * alpha[i][r] + sm;
#pragma unroll
        for (int j = 0; j < 4; ++j) o[i][j][r] *= alpha[i][r];
      }

    // PV: each wave reads only P rows it wrote -> no barrier needed before this
#pragma unroll
    for (int ks = 0; ks < 4; ++ks) {
      bf16x8 bv4[4];
#pragma unroll
      for (int j = 0; j < 4; ++j) {
        int d = j * 16 + c;
        bv4[j] = *(const bf16x8*)&Vs[d * 128 + (((ks * 4 + q) ^ (d & 15)) * 8)];
      }
#pragma unroll
      for (int i = 0; i < 2; ++i) {
        int pr = rbase + i * 16 + c;
        bf16x8 a = *(const bf16x8*)&Ps[pr * 128 + (((ks * 4 + q) ^ (pr & 15)) * 8)];
#pragma unroll
        for (int j = 0; j < 4; ++j)
          o[i][j] = __builtin_amdgcn_mfma_f32_16x16x32_bf16(a, bv4[j], o[i][j], 0, 0, 0);
      }
    }
    __syncthreads();  // Ks/Vs consumed by all waves before next staging
  }

  // epilogue: att [B*T][H*D] bf16
#pragma unroll
  for (int i = 0; i < 2; ++i)
#pragma unroll
    for (int r = 0; r < 4; ++r) {
      float inv = 1.f / lrow[i][r];
      int t = qt * 128 + rbase + i * 16 + q * 4 + r;
#pragma unroll
      for (int j = 0; j < 4; ++j)
        att[((size_t)(b * T_CTX + t)) * HD + h * HS + j * 16 + c] = f2bf(o[i][j][r] * inv);
    }
}

// ---------------- output projection: out = att @ Wo + bo (fp32 out) ----------------
__global__ __launch_bounds__(256) void k_gemm_out(
    const u16* __restrict__ attb, const u16* __restrict__ Wot,
    const float* __restrict__ bo, float* __restrict__ out) {
  __shared__ u16 As[128 * 32], Bs[128 * 32];
  const int m0 = blockIdx.x * 128, n0 = blockIdx.y * 128;
  f32x4 acc[4][4];
  gemm_core(attb, Wot, m0, n0, As, Bs, acc);
  const int lane = threadIdx.x & 63, w = threadIdx.x >> 6;
  const int wm = (w >> 1) * 64, wn = (w & 1) * 64, q = lane >> 4, l16 = lane & 15;
#pragma unroll
  for (int j = 0; j < 4; ++j) {
    int n = n0 + wn + j * 16 + l16;
    float bn = bo[n];
#pragma unroll
    for (int i = 0; i < 4; ++i)
#pragma unroll
      for (int r = 0; r < 4; ++r) {
        int m = m0 + wm + i * 16 + q * 4 + r;
        out[(size_t)m * NE + n] = acc[i][j][r] + bn;
      }
  }
}

extern "C" void kernel_launch(void* const* d_in, const int* in_sizes, int n_in,
                              void* d_out, int out_size, void* d_ws, size_t ws_size,
                              hipStream_t stream) {
  (void)in_sizes; (void)n_in; (void)out_size; (void)ws_size;
  // setup_inputs order: x, Wk, bk, Wq, bq, Wv, bv, Wo, bo
  const float* x  = (const float*)d_in[0];
  const float* Wk = (const float*)d_in[1];
  const float* bk = (const float*)d_in[2];
  const float* Wq = (const float*)d_in[3];
  const float* bq = (const float*)d_in[4];
  const float* Wv = (const float*)d_in[5];
  const float* bv = (const float*)d_in[6];
  const float* Wo = (const float*)d_in[7];
  const float* bo = (const float*)d_in[8];
  float* out = (float*)d_out;

  // workspace layout (u16 elements), total 28M u16 = 56 MB
  u16* xb   = (u16*)d_ws;                       // 4M
  u16* Wt   = xb   + (size_t)BT * NE;           // 3M  (Wq_t, Wk_t, Wv_t)
  u16* Wot  = Wt   + (size_t)3 * NE * HD;       // 1M
  u16* Qw   = Wot  + (size_t)NE * HD;           // 4M  [B,H,T,D]
  u16* Kw   = Qw   + (size_t)BT * HD;           // 4M  [B,H,T,D]
  u16* Vw   = Kw   + (size_t)BT * HD;           // 4M  [B,H,T,D]
  u16* Vtw  = Vw   + (size_t)BT * HD;           // 4M  [B,H,D,T]
  u16* attw = Vtw  + (size_t)BT * HD;           // 4M  [B*T][H*D]

  k_prep_x<<<dim3(BT * NE / 4 / 256), 256, 0, stream>>>(x, xb);
  k_prep_w<<<dim3(16, 16, 4), 256, 0, stream>>>(
      Wq, Wk, Wv, Wo, Wt, Wt + (size_t)NE * HD, Wt + (size_t)2 * NE * HD, Wot);
  k_gemm_qkv<<<dim3(32, 8, 3), 256, 0, stream>>>(xb, Wt, bq, bk, bv, Qw);
  k_vt<<<dim3(32, 32), 256, 0, stream>>>(Vw, Vtw);
  k_attn<<<dim3(16, 32), 256, 0, stream>>>(Qw, Kw, Vtw, attw);
  k_gemm_out<<<dim3(32, 8), 256, 0, stream>>>(attw, Wot, bo, out);
}

// Round 2
// 218.394 us; speedup vs baseline: 1.0907x; 1.0907x over previous
//
#include <hip/hip_runtime.h>

#define NH 16
#define HS 64
#define T_CTX 2048
#define NE 1024
#define NB 2
#define BT (NB*T_CTX)      // 4096 rows
#define HD (NH*HS)         // 1024

typedef unsigned short u16;
typedef __bf16 bf16_t;
typedef bf16_t bf16x8 __attribute__((ext_vector_type(8)));
typedef float f32x4 __attribute__((ext_vector_type(4)));
typedef u16 u16x8 __attribute__((ext_vector_type(8)));
typedef u16 u16x4 __attribute__((ext_vector_type(4)));

#define GLDS(gp, lp) __builtin_amdgcn_global_load_lds( \
    (const __attribute__((address_space(1))) void*)(gp), \
    (__attribute__((address_space(3))) void*)(lp), 16, 0, 0)

__device__ __forceinline__ u16 f2bf(float f) {
  union { float f; unsigned u; } x; x.f = f;
  return (u16)((x.u + 0x7fffu + ((x.u >> 16) & 1u)) >> 16);
}
__device__ __forceinline__ float bf2f(u16 u) {
  union { unsigned u; float f; } x; x.u = ((unsigned)u) << 16;
  return x.f;
}

// ---------------- prep: x fp32 -> bf16 (same layout) ----------------
__global__ __launch_bounds__(256) void k_prep_x(const float* __restrict__ x,
                                                u16* __restrict__ xb) {
  int i = blockIdx.x * blockDim.x + threadIdx.x;   // one float4 each
  float4 v = ((const float4*)x)[i];
  ushort4 o;
  o.x = f2bf(v.x); o.y = f2bf(v.y); o.z = f2bf(v.z); o.w = f2bf(v.w);
  ((ushort4*)xb)[i] = o;
}

// ------------- prep: W [K,N] fp32 -> Wt [N,K] bf16 (transpose) -------------
__global__ __launch_bounds__(256) void k_prep_w(
    const float* __restrict__ W0, const float* __restrict__ W1,
    const float* __restrict__ W2, const float* __restrict__ W3,
    u16* __restrict__ T0, u16* __restrict__ T1,
    u16* __restrict__ T2, u16* __restrict__ T3) {
  const float* W; u16* T;
  switch (blockIdx.z) {
    case 0: W = W0; T = T0; break;
    case 1: W = W1; T = T1; break;
    case 2: W = W2; T = T2; break;
    default: W = W3; T = T3; break;
  }
  __shared__ u16 tile[64 * 72];              // [n][k], stride 72 (16B-aligned rows)
  int k0 = blockIdx.x * 64, n0 = blockIdx.y * 64;
  int tid = threadIdx.x;
#pragma unroll
  for (int it = 0; it < 4; ++it) {
    int ci = tid + it * 256;                 // 1024 chunks of float4
    int k = ci >> 4, c = ci & 15;
    float4 v = *(const float4*)&W[(size_t)(k0 + k) * NE + n0 + c * 4];
    int n = c * 4;
    tile[(n + 0) * 72 + k] = f2bf(v.x);
    tile[(n + 1) * 72 + k] = f2bf(v.y);
    tile[(n + 2) * 72 + k] = f2bf(v.z);
    tile[(n + 3) * 72 + k] = f2bf(v.w);
  }
  __syncthreads();
#pragma unroll
  for (int it = 0; it < 2; ++it) {
    int co = tid + it * 256;                 // 512 chunks of 8 u16
    int n = co >> 3, c = co & 7;
    u16x8 v = *(const u16x8*)&tile[n * 72 + c * 8];
    *(u16x8*)&T[(size_t)(n0 + n) * NE + k0 + c * 8] = v;
  }
}

// ---------------- GEMM core: 128x128 tile, BK=32, m97 pattern ----------------
__device__ __forceinline__ void gemm_core(
    const u16* __restrict__ A, const u16* __restrict__ Bt,
    int m0, int n0, u16* As, u16* Bs, f32x4 (&acc)[4][4]) {
  const int tid = threadIdx.x, lane = tid & 63, w = tid >> 6;
  const int wm = (w >> 1) * 64, wn = (w & 1) * 64;
  const int q = lane >> 4, l16 = lane & 15;
#pragma unroll
  for (int i = 0; i < 4; ++i)
#pragma unroll
    for (int j = 0; j < 4; ++j)
#pragma unroll
      for (int r = 0; r < 4; ++r) acc[i][j][r] = 0.f;

  for (int k0 = 0; k0 < NE; k0 += 32) {
#pragma unroll
    for (int s2 = 0; s2 < 2; ++s2) {
      int ci = w * 64 + lane + s2 * 256;     // 512 chunks of 16B per matrix
      int row = ci >> 2, cc = ci & 3;
      GLDS(A  + (size_t)(m0 + row) * NE + k0 + cc * 8, As + (size_t)(w * 64 + s2 * 256) * 8);
      GLDS(Bt + (size_t)(n0 + row) * NE + k0 + cc * 8, Bs + (size_t)(w * 64 + s2 * 256) * 8);
    }
    __syncthreads();
    bf16x8 av[4], bv4[4];
#pragma unroll
    for (int i = 0; i < 4; ++i) av[i]  = *(const bf16x8*)&As[(wm + i * 16 + l16) * 32 + q * 8];
#pragma unroll
    for (int j = 0; j < 4; ++j) bv4[j] = *(const bf16x8*)&Bs[(wn + j * 16 + l16) * 32 + q * 8];
#pragma unroll
    for (int i = 0; i < 4; ++i)
#pragma unroll
      for (int j = 0; j < 4; ++j)
        acc[i][j] = __builtin_amdgcn_mfma_f32_16x16x32_bf16(av[i], bv4[j], acc[i][j], 0, 0, 0);
    __syncthreads();
  }
}

// ------ QKV projection: C = x@W + b ; write bf16 [B,H,T,D]; scale folded into Q ------
__global__ __launch_bounds__(256) void k_gemm_qkv(
    const u16* __restrict__ xb, const u16* __restrict__ Wt,
    const float* __restrict__ bq, const float* __restrict__ bk,
    const float* __restrict__ bv, u16* __restrict__ qkv) {
  __shared__ u16 As[128 * 32], Bs[128 * 32];
  const int z = blockIdx.z;
  const u16* W = Wt + (size_t)z * NE * HD;
  const float* bias = (z == 0) ? bq : (z == 1 ? bk : bv);
  u16* dst = qkv + (size_t)z * BT * HD;
  // softmax scale 1/sqrt(E) and log2(e) folded into Q so attention uses exp2
  const float scale = (z == 0) ? 0.03125f * 1.4426950408889634f : 1.0f;
  const int m0 = blockIdx.x * 128, n0 = blockIdx.y * 128;
  f32x4 acc[4][4];
  gemm_core(xb, W, m0, n0, As, Bs, acc);
  const int lane = threadIdx.x & 63, w = threadIdx.x >> 6;
  const int wm = (w >> 1) * 64, wn = (w & 1) * 64, q = lane >> 4, l16 = lane & 15;
#pragma unroll
  for (int j = 0; j < 4; ++j) {
    int n = n0 + wn + j * 16 + l16;
    float bn = bias[n];
    int h = n >> 6, d = n & 63;
#pragma unroll
    for (int i = 0; i < 4; ++i)
#pragma unroll
      for (int r = 0; r < 4; ++r) {
        int m = m0 + wm + i * 16 + q * 4 + r;
        int bb = m >> 11, t = m & (T_CTX - 1);
        dst[(((size_t)(bb * NH + h)) * T_CTX + t) * HS + d] =
            f2bf((acc[i][j][r] + bn) * scale);
      }
  }
}

// ---------------- V [B,H,T,D] -> Vt [B,H,D,T] ----------------
__global__ __launch_bounds__(256) void k_vt(const u16* __restrict__ V,
                                            u16* __restrict__ Vt) {
  int bh = blockIdx.y, t0 = blockIdx.x * 64;
  const u16* src = V + (size_t)bh * T_CTX * HS;
  u16* dst = Vt + (size_t)bh * HS * T_CTX;
  __shared__ u16 tile[64 * 72];              // [d][t]
  int tid = threadIdx.x;
#pragma unroll
  for (int it = 0; it < 2; ++it) {
    int ci = tid + it * 256;                 // 512 chunks
    int t = ci >> 3, c = ci & 7;
    u16x8 v = *(const u16x8*)&src[(size_t)(t0 + t) * HS + c * 8];
#pragma unroll
    for (int e = 0; e < 8; ++e) tile[(c * 8 + e) * 72 + t] = v[e];
  }
  __syncthreads();
#pragma unroll
  for (int it = 0; it < 2; ++it) {
    int co = tid + it * 256;
    int d = co >> 3, c = co & 7;
    u16x8 v = *(const u16x8*)&tile[d * 72 + c * 8];
    *(u16x8*)&dst[(size_t)d * T_CTX + t0 + c * 8] = v;
  }
}

// ------------- flash attention, S^T layout + split-K (2 parts) -------------
// Grid x: 32 = 16 qt * 2 parts, big-first; y: 32 bh. Writes unnormalized
// partial o (bf16) + per-row (m, l) f32; k_combine merges.
__global__ __launch_bounds__(256, 2) void k_attn(
    const u16* __restrict__ Qw, const u16* __restrict__ Kw,
    const u16* __restrict__ Vtw, u16* __restrict__ opart,
    float* __restrict__ ml) {
  __shared__ u16 Ks[128 * 64];               // [key][d], 16B-chunk ^= key&7
  __shared__ u16 Vs[64 * 128];               // [d][key], 16B-chunk ^= d&15
  __shared__ u16 Ps[128 * 128];              // [qrow][key], 16B-chunk ^= qrow&15

  const int bh = blockIdx.y;
  const int x = blockIdx.x;
  const int qt = 15 - (x >> 1);              // big tiles dispatch first
  const int part = x & 1;
  const int n = qt + 1;
  const int half = (n + 1) >> 1;
  const int klo = part ? half : 0;
  const int khi = part ? n : half;
  const int qbase = qt * 128;

  const u16* Qp = Qw + (size_t)bh * T_CTX * HS;
  const u16* Kp = Kw + (size_t)bh * T_CTX * HS;
  const u16* Vp = Vtw + (size_t)bh * HS * T_CTX;

  const int tid = threadIdx.x, lane = tid & 63, w = tid >> 6;
  const int q = lane >> 4, c = lane & 15;
  const int rbase = w * 32;                  // wave's 32 q-rows within tile

  // Q fragments (B-operand: lane n=qrow, k=d) straight from global
  bf16x8 aq[2][2];
#pragma unroll
  for (int i = 0; i < 2; ++i)
#pragma unroll
    for (int s = 0; s < 2; ++s)
      aq[i][s] = *(const bf16x8*)&Qp[(size_t)(qbase + rbase + i * 16 + c) * HS + s * 32 + q * 8];

  f32x4 o[2][4];
  float mrow[2], lrow[2];                    // state for qrow = rbase + j2*16 + c
#pragma unroll
  for (int i = 0; i < 2; ++i) {
    mrow[i] = -__builtin_inff(); lrow[i] = 0.f;
#pragma unroll
    for (int j = 0; j < 4; ++j)
#pragma unroll
      for (int r = 0; r < 4; ++r) o[i][j][r] = 0.f;
  }

  for (int kt = klo; kt < khi; ++kt) {
    const int k0 = kt * 128;
#pragma unroll
    for (int it = 0; it < 4; ++it) {
      int ci = tid + it * 256;
      int row = ci >> 3, cc = ci & 7;
      *(u16x8*)&Ks[row * 64 + (cc ^ (row & 7)) * 8] =
          *(const u16x8*)&Kp[(size_t)(k0 + row) * HS + cc * 8];
      int d = ci >> 4, c2 = ci & 15;
      *(u16x8*)&Vs[d * 128 + (c2 ^ (d & 15)) * 8] =
          *(const u16x8*)&Vp[(size_t)d * T_CTX + k0 + c2 * 8];
    }
    __syncthreads();

    // S^T = K Q^T : lane holds qrow = rbase+j2*16+c, keys = i2*16+q*4+{0..3}
    f32x4 s[8][2];
#pragma unroll
    for (int i2 = 0; i2 < 8; ++i2)
#pragma unroll
      for (int j2 = 0; j2 < 2; ++j2)
#pragma unroll
        for (int r = 0; r < 4; ++r) s[i2][j2][r] = 0.f;
#pragma unroll
    for (int i2 = 0; i2 < 8; ++i2) {
      int krow = i2 * 16 + c;
      bf16x8 kf0 = *(const bf16x8*)&Ks[krow * 64 + ((0 + q) ^ (krow & 7)) * 8];
      bf16x8 kf1 = *(const bf16x8*)&Ks[krow * 64 + ((4 + q) ^ (krow & 7)) * 8];
#pragma unroll
      for (int j2 = 0; j2 < 2; ++j2) {
        s[i2][j2] = __builtin_amdgcn_mfma_f32_16x16x32_bf16(kf0, aq[j2][0], s[i2][j2], 0, 0, 0);
        s[i2][j2] = __builtin_amdgcn_mfma_f32_16x16x32_bf16(kf1, aq[j2][1], s[i2][j2], 0, 0, 0);
      }
    }

    if (kt == qt) {  // causal mask on diagonal tile
#pragma unroll
      for (int i2 = 0; i2 < 8; ++i2)
#pragma unroll
        for (int j2 = 0; j2 < 2; ++j2)
#pragma unroll
          for (int r = 0; r < 4; ++r) {
            int key = k0 + i2 * 16 + q * 4 + r;
            int qrow = qbase + rbase + j2 * 16 + c;
            if (key > qrow) s[i2][j2][r] = -__builtin_inff();
          }
    }

    float alpha[2];
#pragma unroll
    for (int j2 = 0; j2 < 2; ++j2) {
      float mx = s[0][j2][0];
#pragma unroll
      for (int i2 = 0; i2 < 8; ++i2)
#pragma unroll
        for (int r = 0; r < 4; ++r) mx = fmaxf(mx, s[i2][j2][r]);
      mx = fmaxf(mx, __shfl_xor(mx, 16, 64));
      mx = fmaxf(mx, __shfl_xor(mx, 32, 64));
      float mn = fmaxf(mrow[j2], mx);
      alpha[j2] = __builtin_amdgcn_exp2f(mrow[j2] - mn);
      mrow[j2] = mn;
    }

#pragma unroll
    for (int j2 = 0; j2 < 2; ++j2) {
      const int qrow = rbase + j2 * 16 + c;
      float rs = 0.f;
#pragma unroll
      for (int i2 = 0; i2 < 8; ++i2) {
        u16x4 pk;
#pragma unroll
        for (int r = 0; r < 4; ++r) {
          float p = __builtin_amdgcn_exp2f(s[i2][j2][r] - mrow[j2]);
          rs += p;
          pk[r] = f2bf(p);
        }
        // write 4 consecutive keys: chunk16 = i2*2 + (q>>1), half = q&1
        *(u16x4*)&Ps[qrow * 128 + (((i2 * 2 + (q >> 1)) ^ c) * 8) + (q & 1) * 4] = pk;
      }
      rs += __shfl_xor(rs, 16, 64);
      rs += __shfl_xor(rs, 32, 64);
      lrow[j2] = lrow[j2] * alpha[j2] + rs;
    }

    // rescale o by alpha (gather per-row alpha from lanes 0..15)
#pragma unroll
    for (int i = 0; i < 2; ++i) {
#pragma unroll
      for (int r = 0; r < 4; ++r) {
        float af = __shfl(alpha[i], q * 4 + r, 64);
#pragma unroll
        for (int j = 0; j < 4; ++j) o[i][j][r] *= af;
      }
    }

    // PV: A = P (rows this wave wrote), B = V^T fragments
#pragma unroll
    for (int ks = 0; ks < 4; ++ks) {
      bf16x8 bv4[4];
#pragma unroll
      for (int j = 0; j < 4; ++j) {
        int d = j * 16 + c;
        bv4[j] = *(const bf16x8*)&Vs[d * 128 + (((ks * 4 + q) ^ c) * 8)];
      }
#pragma unroll
      for (int i = 0; i < 2; ++i) {
        int qrow = rbase + i * 16 + c;
        bf16x8 a = *(const bf16x8*)&Ps[qrow * 128 + (((ks * 4 + q) ^ c) * 8)];
#pragma unroll
        for (int j = 0; j < 4; ++j)
          o[i][j] = __builtin_amdgcn_mfma_f32_16x16x32_bf16(a, bv4[j], o[i][j], 0, 0, 0);
      }
    }
    __syncthreads();
  }

  // epilogue: partial (m, l) once per row (q==0 lanes), unnormalized o in bf16
  const size_t prow0 = (size_t)(part * 32 + bh) * T_CTX;
  if (q == 0) {
#pragma unroll
    for (int i = 0; i < 2; ++i) {
      size_t t = prow0 + qbase + rbase + i * 16 + c;
      ml[t * 2 + 0] = mrow[i];
      ml[t * 2 + 1] = lrow[i];
    }
  }
#pragma unroll
  for (int i = 0; i < 2; ++i)
#pragma unroll
    for (int r = 0; r < 4; ++r) {
      size_t t = prow0 + qbase + rbase + i * 16 + q * 4 + r;
#pragma unroll
      for (int j = 0; j < 4; ++j)
        opart[t * 64 + j * 16 + c] = f2bf(o[i][j][r]);
    }
}

// ------------- combine the 2 split-K partials -> att [B*T][H*D] bf16 -------------
__global__ __launch_bounds__(256) void k_combine(
    const u16* __restrict__ opart, const float* __restrict__ ml,
    u16* __restrict__ att) {
  int idx = blockIdx.x * 256 + threadIdx.x;   // 65536 rows * 8 octets
  int row = idx >> 3, oct = idx & 7;
  float m0 = ml[(size_t)row * 2], l0 = ml[(size_t)row * 2 + 1];
  float m1 = ml[((size_t)65536 + row) * 2], l1 = ml[((size_t)65536 + row) * 2 + 1];
  float mm = fmaxf(m0, m1);
  float w0 = __builtin_amdgcn_exp2f(m0 - mm);
  float w1 = __builtin_amdgcn_exp2f(m1 - mm);
  float inv = 1.f / (w0 * l0 + w1 * l1);
  w0 *= inv; w1 *= inv;
  u16x8 a = *(const u16x8*)&opart[(size_t)row * 64 + oct * 8];
  u16x8 b = *(const u16x8*)&opart[(size_t)65536 * 64 + (size_t)row * 64 + oct * 8];
  u16x8 ov;
#pragma unroll
  for (int e = 0; e < 8; ++e) ov[e] = f2bf(w0 * bf2f(a[e]) + w1 * bf2f(b[e]));
  int bh = row >> 11, t = row & 2047, bb = bh >> 4, h = bh & 15;
  *(u16x8*)&att[((size_t)(bb * T_CTX + t)) * HD + h * 64 + oct * 8] = ov;
}

// ---------------- output projection: out = att @ Wo + bo (fp32 out) ----------------
__global__ __launch_bounds__(256) void k_gemm_out(
    const u16* __restrict__ attb, const u16* __restrict__ Wot,
    const float* __restrict__ bo, float* __restrict__ out) {
  __shared__ u16 As[128 * 32], Bs[128 * 32];
  const int m0 = blockIdx.x * 128, n0 = blockIdx.y * 128;
  f32x4 acc[4][4];
  gemm_core(attb, Wot, m0, n0, As, Bs, acc);
  const int lane = threadIdx.x & 63, w = threadIdx.x >> 6;
  const int wm = (w >> 1) * 64, wn = (w & 1) * 64, q = lane >> 4, l16 = lane & 15;
#pragma unroll
  for (int j = 0; j < 4; ++j) {
    int n = n0 + wn + j * 16 + l16;
    float bn = bo[n];
#pragma unroll
    for (int i = 0; i < 4; ++i)
#pragma unroll
      for (int r = 0; r < 4; ++r) {
        int m = m0 + wm + i * 16 + q * 4 + r;
        out[(size_t)m * NE + n] = acc[i][j][r] + bn;
      }
  }
}

extern "C" void kernel_launch(void* const* d_in, const int* in_sizes, int n_in,
                              void* d_out, int out_size, void* d_ws, size_t ws_size,
                              hipStream_t stream) {
  (void)in_sizes; (void)n_in; (void)out_size; (void)ws_size;
  // setup_inputs order: x, Wk, bk, Wq, bq, Wv, bv, Wo, bo
  const float* x  = (const float*)d_in[0];
  const float* Wk = (const float*)d_in[1];
  const float* bk = (const float*)d_in[2];
  const float* Wq = (const float*)d_in[3];
  const float* bq = (const float*)d_in[4];
  const float* Wv = (const float*)d_in[5];
  const float* bv = (const float*)d_in[6];
  const float* Wo = (const float*)d_in[7];
  const float* bo = (const float*)d_in[8];
  float* out = (float*)d_out;

  // workspace layout (u16 elements), total 28M u16 = 56 MB, with overlays:
  //   xb (dead after qkv GEMM)  <- attw
  //   Wt (dead after qkv GEMM)  <- ml
  //   Vw (dead after k_vt)      <- opart (8M u16, extends over old Qw gap)
  u16* xb    = (u16*)d_ws;                      // @0,  4M
  u16* Wt    = xb  + (size_t)4  * 1024 * 1024;  // @4M, 3M (Wq_t, Wk_t, Wv_t)
  u16* Wot   = xb  + (size_t)7  * 1024 * 1024;  // @7M, 1M
  u16* Qw    = xb  + (size_t)8  * 1024 * 1024;  // @8M, 4M  [B,H,T,D]
  u16* Kw    = xb  + (size_t)12 * 1024 * 1024;  // @12M,4M  [B,H,T,D]
  u16* Vw    = xb  + (size_t)16 * 1024 * 1024;  // @16M,4M  [B,H,T,D]
  u16* Vtw   = xb  + (size_t)24 * 1024 * 1024;  // @24M,4M  [B,H,D,T]
  u16* opart = Vw;                              // @16M,8M  (2 parts)
  float* ml  = (float*)Wt;                      // @4M, 512K f32
  u16* attw  = xb;                              // @0,  4M  [B*T][H*D]

  k_prep_x<<<dim3(BT * NE / 4 / 256), 256, 0, stream>>>(x, xb);
  k_prep_w<<<dim3(16, 16, 4), 256, 0, stream>>>(
      Wq, Wk, Wv, Wo, Wt, Wt + (size_t)NE * HD, Wt + (size_t)2 * NE * HD, Wot);
  k_gemm_qkv<<<dim3(32, 8, 3), 256, 0, stream>>>(xb, Wt, bq, bk, bv, Qw);
  k_vt<<<dim3(32, 32), 256, 0, stream>>>(Vw, Vtw);
  k_attn<<<dim3(32, 32), 256, 0, stream>>>(Qw, Kw, Vtw, opart, ml);
  k_combine<<<dim3(2048), 256, 0, stream>>>(opart, ml, attw);
  k_gemm_out<<<dim3(32, 8), 256, 0, stream>>>(attw, Wot, bo, out);
}